// Round 5
// baseline (739.215 us; speedup 1.0000x reference)
//
#include <hip/hip_runtime.h>
#include <hip/hip_bf16.h>
#include <math.h>

typedef __attribute__((ext_vector_type(8))) short bf16x8;
typedef __attribute__((ext_vector_type(4))) float f32x4;

__device__ __forceinline__ float b2f(unsigned short u) {
    unsigned int v = ((unsigned int)u) << 16;
    return __uint_as_float(v);
}
__device__ __forceinline__ unsigned short f2b(float f) {
    __hip_bfloat16 h = __float2bfloat16(f);
    return *reinterpret_cast<unsigned short*>(&h);
}
// truncation split: hi = top 16 bits, lo = RNE(v - hi). residual ~2^-17 |v|
__device__ __forceinline__ void split_trunc(float v, short& h, short& l) {
    unsigned int ui = __float_as_uint(v);
    h = (short)(ui >> 16);
    float hf = __uint_as_float(ui & 0xffff0000u);
    l = (short)f2b(v - hf);
}

// ============ prep (fused): conv/w3 weights | fc weights | expert weights ============
__global__ __launch_bounds__(256) void prep_all(
    const float* __restrict__ w1, const float* __restrict__ w2, const float* __restrict__ w3,
    const float* __restrict__ ew3, const float* __restrict__ fw,
    const float* __restrict__ ew1, const float* __restrict__ ew2,
    unsigned short* __restrict__ wb1h, unsigned short* __restrict__ wb1l,
    unsigned short* __restrict__ w2h, unsigned short* __restrict__ w2l,
    unsigned short* __restrict__ w3h, unsigned short* __restrict__ w3l,
    float* __restrict__ w3t,
    unsigned short* __restrict__ fh, unsigned short* __restrict__ fl,
    unsigned short* __restrict__ t1, unsigned short* __restrict__ t2) {
    __shared__ float lds_f[64 * 65];
    int b = blockIdx.x;
    int t = threadIdx.x;
    if (b < 448) {
        int tid = b * 256 + t;
        if (tid < 8192) {
            int k = tid >> 8, r = tid & 255;
            int c = r >> 6, ky = (r >> 3) & 7, kx = r & 7;
            float v = w1[tid];
            unsigned short h = f2b(v);
            int d = ((ky * 2 + (k >> 4)) * 16 + (k & 15)) * 32 + c * 8 + kx;
            wb1h[d] = h;
            wb1l[d] = f2b(v - b2f(h));
        } else if (tid < 8192 + 32768) {
            int i = tid - 8192;
            int n = i >> 9, r = i & 511;
            int c = r >> 4, ky = (r >> 2) & 3, kx = r & 3;
            float v = w2[i];
            unsigned short h = f2b(v);
            int d = ((ky * 4 + kx) * 64 + n) * 32 + c;
            w2h[d] = h;
            w2l[d] = f2b(v - b2f(h));
        } else if (tid < 8192 + 32768 + 36864) {
            int i = tid - 40960;
            int n = i / 576, r = i - n * 576;
            int c = r / 9, s = r - c * 9;
            int ky = s / 3, kx = s - ky * 3;
            float v = w3[i];
            unsigned short h = f2b(v);
            int d = (((ky * 3 + kx) * 2 + (c >> 5)) * 64 + n) * 32 + (c & 31);
            w3h[d] = h;
            w3l[d] = f2b(v - b2f(h));
        } else if (tid < 77824 + 36864) {
            int i = tid - 77824;
            int e = i / 6144, rem = i - e * 6144;
            int a = rem >> 9, k = rem & 511;
            w3t[i] = ew3[e * 6144 + k * 12 + a];
        }
    } else if (b < 840) {
        int bx = b - 448;
        int k0 = (bx % 49) * 64;
        int n0 = (bx / 49) * 64;
        int tx = t & 63, ty = t >> 6;
#pragma unroll
        for (int j = 0; j < 16; j++) {
            int kk = ty + j * 4;
            int kp = k0 + kk;
            int p = kp >> 6, c = kp & 63;
            lds_f[kk * 65 + tx] = fw[(c * 49 + p) * 512 + n0 + tx];
        }
        __syncthreads();
#pragma unroll
        for (int j = 0; j < 16; j++) {
            int r = ty + j * 4;
            float v = lds_f[tx * 65 + r];
            unsigned short hh = f2b(v);
            long d = (long)(n0 + r) * 3136 + k0 + tx;
            fh[d] = hh;
            fl[d] = f2b(v - b2f(hh));
        }
    } else {
        int i = b - 840;
        int h0 = (i & 15) * 32;
        int d0 = ((i >> 4) & 15) * 32;
        int z = i >> 8;
        int e = z % 6;
        const float* src = (z < 6) ? (ew1 + e * 262144) : (ew2 + e * 262144);
        unsigned short* dst = (z < 6) ? (t1 + e * 262144) : (t2 + e * 262144);
        int tx = t & 31, ty = t >> 5;
#pragma unroll
        for (int j = 0; j < 4; j++)
            lds_f[(ty + j * 8) * 33 + tx] = src[(d0 + ty + j * 8) * 512 + h0 + tx];
        __syncthreads();
#pragma unroll
        for (int j = 0; j < 4; j++)
            dst[(h0 + ty + j * 8) * 512 + (d0 + tx)] = f2b(lds_f[tx * 33 + ty + j * 8]);
    }
}

// ============ conv1: unchanged from round 4 ============
__global__ __launch_bounds__(256, 4) void conv1_k(
    const float* __restrict__ x, const unsigned short* __restrict__ wbh,
    const unsigned short* __restrict__ wbl, const float* __restrict__ b1,
    unsigned short* __restrict__ yhi, unsigned short* __restrict__ ylo) {
    __shared__ bf16x8 wlds[8][4][64];
    int t = threadIdx.x;
    {
        int tab = t >> 6, ln = t & 63;
        const unsigned short* sb = ((tab < 2) ? wbh : wbl) +
            ((ln & 15) * 32 + (ln >> 4) * 8 + (tab & 1) * 512);
#pragma unroll
        for (int k = 0; k < 8; k++)
            wlds[k][tab][ln] = *(const bf16x8*)(sb + k * 1024);
    }
    int swz = (blockIdx.x & 7) * 800 + (blockIdx.x >> 3);
    int wave = t >> 6, lane = t & 63, l16 = lane & 15, quad = lane >> 4;
    int px0 = swz * 128 + wave * 32;
    const float* abase[2];
#pragma unroll
    for (int i = 0; i < 2; i++) {
        int px = px0 + i * 16 + l16;
        int n = px / 400;
        int rem = px - n * 400;
        int oy = rem / 20;
        int ox = rem - oy * 20;
        abase[i] = x + (long)n * 28224 + quad * 7056 + oy * 4 * 84 + ox * 4;
    }
    f32x4 acc[2][2];
#pragma unroll
    for (int i = 0; i < 2; i++)
#pragma unroll
        for (int j = 0; j < 2; j++)
#pragma unroll
            for (int r = 0; r < 4; r++) acc[i][j][r] = 0.f;
    __syncthreads();
    float4 buf[4][4];
#pragma unroll
    for (int r = 0; r < 3; r++) {
        __builtin_amdgcn_sched_barrier(0);
#pragma unroll
        for (int i = 0; i < 2; i++) {
            const float* p = abase[i] + r * 84;
            buf[r][i * 2] = *(const float4*)p;
            buf[r][i * 2 + 1] = *(const float4*)(p + 4);
        }
        __builtin_amdgcn_sched_barrier(0);
    }
#pragma unroll
    for (int ky = 0; ky < 8; ky++) {
        if (ky < 5) {
            __builtin_amdgcn_sched_barrier(0);
#pragma unroll
            for (int i = 0; i < 2; i++) {
                const float* p = abase[i] + (ky + 3) * 84;
                buf[(ky + 3) & 3][i * 2] = *(const float4*)p;
                buf[(ky + 3) & 3][i * 2 + 1] = *(const float4*)(p + 4);
            }
            __builtin_amdgcn_sched_barrier(0);
        }
        bf16x8 bh0 = wlds[ky][0][lane];
        bf16x8 bh1 = wlds[ky][1][lane];
        bf16x8 bl0 = wlds[ky][2][lane];
        bf16x8 bl1 = wlds[ky][3][lane];
        bf16x8 ah[2], al[2];
#pragma unroll
        for (int i = 0; i < 2; i++) {
            const float4& c0 = buf[ky & 3][i * 2];
            const float4& c1 = buf[ky & 3][i * 2 + 1];
            float v[8] = {c0.x, c0.y, c0.z, c0.w, c1.x, c1.y, c1.z, c1.w};
#pragma unroll
            for (int j = 0; j < 8; j++) {
                short hh, ll;
                split_trunc(v[j], hh, ll);
                ah[i][j] = hh;
                al[i][j] = ll;
            }
        }
#pragma unroll
        for (int i = 0; i < 2; i++) {
            acc[i][0] = __builtin_amdgcn_mfma_f32_16x16x32_bf16(ah[i], bh0, acc[i][0], 0, 0, 0);
            acc[i][0] = __builtin_amdgcn_mfma_f32_16x16x32_bf16(al[i], bh0, acc[i][0], 0, 0, 0);
            acc[i][0] = __builtin_amdgcn_mfma_f32_16x16x32_bf16(ah[i], bl0, acc[i][0], 0, 0, 0);
            acc[i][1] = __builtin_amdgcn_mfma_f32_16x16x32_bf16(ah[i], bh1, acc[i][1], 0, 0, 0);
            acc[i][1] = __builtin_amdgcn_mfma_f32_16x16x32_bf16(al[i], bh1, acc[i][1], 0, 0, 0);
            acc[i][1] = __builtin_amdgcn_mfma_f32_16x16x32_bf16(ah[i], bl1, acc[i][1], 0, 0, 0);
        }
    }
    float bias0 = b1[l16], bias1 = b1[16 + l16];
#pragma unroll
    for (int i = 0; i < 2; i++) {
#pragma unroll
        for (int r = 0; r < 4; r++) {
            long px = px0 + i * 16 + quad * 4 + r;
            long o = px * 32;
            float v0 = fmaxf(acc[i][0][r] + bias0, 0.f);
            float v1 = fmaxf(acc[i][1][r] + bias1, 0.f);
            short h0, l0, h1, l1;
            split_trunc(v0, h0, l0);
            split_trunc(v1, h1, l1);
            yhi[o + l16] = (unsigned short)h0;
            ylo[o + l16] = (unsigned short)l0;
            yhi[o + 16 + l16] = (unsigned short)h1;
            ylo[o + 16 + l16] = (unsigned short)l1;
        }
    }
}

// ============ conv2/3: 1-wave blocks, 32 px/wave, full K-unroll, pinned
// ping-pong prefetch: entire next chunk (A+B, 12 loads) issued before current
// chunk's MFMAs -> compiler emits counted vmcnt, loads in flight across the
// whole MFMA phase. No LDS, no barriers. ============
template <int C, int IH, int IW, int OH, int OW, int S, int KH, int KW>
__global__ __launch_bounds__(64, 3) void convm_k(
    const unsigned short* __restrict__ xhi, const unsigned short* __restrict__ xlo,
    const unsigned short* __restrict__ whi, const unsigned short* __restrict__ wlo,
    const float* __restrict__ bias,
    unsigned short* __restrict__ yhi, unsigned short* __restrict__ ylo) {
    constexpr int CH = C / 32;
    constexpr int NCHUNK = KH * KW * CH;
    int lane = threadIdx.x, l16 = lane & 15, quad = lane >> 4;
    int pxbase = blockIdx.x * 32;
    long xoff[2];
#pragma unroll
    for (int i = 0; i < 2; i++) {
        int px = pxbase + i * 16 + l16;
        int n = px / (OH * OW);
        int rem = px - n * (OH * OW);
        int oy = rem / OW;
        int ox = rem - oy * OW;
        xoff[i] = (((long)n * IH + oy * S) * IW + ox * S) * C + quad * 8;
    }
    f32x4 acc[2][4];
#pragma unroll
    for (int i = 0; i < 2; i++)
#pragma unroll
        for (int j = 0; j < 4; j++)
#pragma unroll
            for (int r = 0; r < 4; r++) acc[i][j][r] = 0.f;
    bf16x8 Ah[2][2], Al[2][2], Bh[2][4], Bl[2][4];
    // prologue: slot 0 = chunk 0 (koff 0), pinned
    __builtin_amdgcn_sched_barrier(0);
#pragma unroll
    for (int i = 0; i < 2; i++) {
        Ah[0][i] = *(const bf16x8*)(xhi + xoff[i]);
        Al[0][i] = *(const bf16x8*)(xlo + xoff[i]);
    }
#pragma unroll
    for (int j = 0; j < 4; j++) {
        Bh[0][j] = *(const bf16x8*)(whi + (long)(j * 16 + l16) * 32 + quad * 8);
        Bl[0][j] = *(const bf16x8*)(wlo + (long)(j * 16 + l16) * 32 + quad * 8);
    }
    __builtin_amdgcn_sched_barrier(0);
#pragma unroll
    for (int ck = 0; ck < NCHUNK; ck++) {
        const int cur = ck & 1;
        if (ck + 1 < NCHUNK) {
            const int c1 = ck + 1;
            const int kyx = c1 / CH;
            const int ch = c1 - kyx * CH;
            const int ky = kyx / KW, kx = kyx - ky * KW;
            const long k1 = ((long)(ky * IW + kx)) * C + ch * 32;
            __builtin_amdgcn_sched_barrier(0);
#pragma unroll
            for (int i = 0; i < 2; i++) {
                Ah[cur ^ 1][i] = *(const bf16x8*)(xhi + xoff[i] + k1);
                Al[cur ^ 1][i] = *(const bf16x8*)(xlo + xoff[i] + k1);
            }
#pragma unroll
            for (int j = 0; j < 4; j++) {
                Bh[cur ^ 1][j] = *(const bf16x8*)(whi + ((long)c1 * 64 + j * 16 + l16) * 32 + quad * 8);
                Bl[cur ^ 1][j] = *(const bf16x8*)(wlo + ((long)c1 * 64 + j * 16 + l16) * 32 + quad * 8);
            }
            __builtin_amdgcn_sched_barrier(0);
        }
#pragma unroll
        for (int i = 0; i < 2; i++)
#pragma unroll
            for (int j = 0; j < 4; j++) {
                acc[i][j] = __builtin_amdgcn_mfma_f32_16x16x32_bf16(Ah[cur][i], Bh[cur][j], acc[i][j], 0, 0, 0);
                acc[i][j] = __builtin_amdgcn_mfma_f32_16x16x32_bf16(Ah[cur][i], Bl[cur][j], acc[i][j], 0, 0, 0);
                acc[i][j] = __builtin_amdgcn_mfma_f32_16x16x32_bf16(Al[cur][i], Bh[cur][j], acc[i][j], 0, 0, 0);
            }
    }
#pragma unroll
    for (int i = 0; i < 2; i++)
#pragma unroll
        for (int j = 0; j < 4; j++) {
            int col = j * 16 + l16;
            float bv = bias[col];
#pragma unroll
            for (int r = 0; r < 4; r++) {
                int prow = pxbase + i * 16 + quad * 4 + r;
                float v = fmaxf(acc[i][j][r] + bv, 0.f);
                unsigned short h = f2b(v);
                yhi[(long)prow * 64 + col] = h;
                ylo[(long)prow * 64 + col] = f2b(v - b2f(h));
            }
        }
}

// ============ fc: 1-wave, 32 rows x 64 cols, K-split x7, full unroll with
// pinned ping-pong prefetch of the next k-step. Block (0,0,0) zeroes cnt. ============
__global__ __launch_bounds__(64, 3) void fc_k(
    const unsigned short* __restrict__ Ahi, const unsigned short* __restrict__ Alo,
    const unsigned short* __restrict__ Bhi, const unsigned short* __restrict__ Blo,
    float* __restrict__ Cp, int* __restrict__ cnt) {
    if (blockIdx.x == 0 && blockIdx.y == 0 && blockIdx.z == 0 && threadIdx.x < 8)
        cnt[threadIdx.x] = 0;
    int lane = threadIdx.x, l16 = lane & 15, quad = lane >> 4;
    int m0 = blockIdx.x * 32, n0 = blockIdx.y * 64;
    int z = blockIdx.z;
    int kBase = z * 448;
    long aoff[2], boff[4];
#pragma unroll
    for (int i = 0; i < 2; i++) aoff[i] = (long)(m0 + i * 16 + l16) * 3136 + kBase + quad * 8;
#pragma unroll
    for (int j = 0; j < 4; j++) boff[j] = (long)(n0 + j * 16 + l16) * 3136 + kBase + quad * 8;
    f32x4 acc[2][4];
#pragma unroll
    for (int i = 0; i < 2; i++)
#pragma unroll
        for (int j = 0; j < 4; j++)
#pragma unroll
            for (int r = 0; r < 4; r++) acc[i][j][r] = 0.f;
    bf16x8 Ah[2][2], Al[2][2], Bh[2][4], Bl[2][4];
    __builtin_amdgcn_sched_barrier(0);
#pragma unroll
    for (int i = 0; i < 2; i++) {
        Ah[0][i] = *(const bf16x8*)(Ahi + aoff[i]);
        Al[0][i] = *(const bf16x8*)(Alo + aoff[i]);
    }
#pragma unroll
    for (int j = 0; j < 4; j++) {
        Bh[0][j] = *(const bf16x8*)(Bhi + boff[j]);
        Bl[0][j] = *(const bf16x8*)(Blo + boff[j]);
    }
    __builtin_amdgcn_sched_barrier(0);
#pragma unroll
    for (int s = 0; s < 14; s++) {
        const int cur = s & 1;
        if (s + 1 < 14) {
            const int k1 = (s + 1) * 32;
            __builtin_amdgcn_sched_barrier(0);
#pragma unroll
            for (int i = 0; i < 2; i++) {
                Ah[cur ^ 1][i] = *(const bf16x8*)(Ahi + aoff[i] + k1);
                Al[cur ^ 1][i] = *(const bf16x8*)(Alo + aoff[i] + k1);
            }
#pragma unroll
            for (int j = 0; j < 4; j++) {
                Bh[cur ^ 1][j] = *(const bf16x8*)(Bhi + boff[j] + k1);
                Bl[cur ^ 1][j] = *(const bf16x8*)(Blo + boff[j] + k1);
            }
            __builtin_amdgcn_sched_barrier(0);
        }
#pragma unroll
        for (int i = 0; i < 2; i++)
#pragma unroll
            for (int j = 0; j < 4; j++) {
                acc[i][j] = __builtin_amdgcn_mfma_f32_16x16x32_bf16(Ah[cur][i], Bh[cur][j], acc[i][j], 0, 0, 0);
                acc[i][j] = __builtin_amdgcn_mfma_f32_16x16x32_bf16(Ah[cur][i], Bl[cur][j], acc[i][j], 0, 0, 0);
                acc[i][j] = __builtin_amdgcn_mfma_f32_16x16x32_bf16(Al[cur][i], Bh[cur][j], acc[i][j], 0, 0, 0);
            }
    }
    float* Cz = Cp + (long)z * 1048576;
#pragma unroll
    for (int i = 0; i < 2; i++)
#pragma unroll
        for (int j = 0; j < 4; j++) {
            int col = n0 + j * 16 + l16;
#pragma unroll
            for (int r = 0; r < 4; r++) {
                int row = m0 + i * 16 + quad * 4 + r;
                Cz[row * 512 + col] = acc[i][j][r];
            }
        }
}

// ============ fin_gate (fused): unchanged ============
__global__ __launch_bounds__(256) void fin_gate(
    const float* __restrict__ Cp, const float* __restrict__ bias,
    const float* __restrict__ gw, const float* __restrict__ gb,
    unsigned short* __restrict__ fb, int* __restrict__ topi, float* __restrict__ topp,
    int* __restrict__ cnt, int* __restrict__ rowlist, int* __restrict__ slotp) {
    __shared__ float frow[512];
    int row = blockIdx.x;
    int t = threadIdx.x;
#pragma unroll
    for (int s = 0; s < 2; s++) {
        int c = t + s * 256;
        long base = (long)row * 512 + c;
        float v = bias[c];
#pragma unroll
        for (int z = 0; z < 7; z++) v += Cp[base + (long)z * 1048576];
        v = fmaxf(v, 0.f);
        fb[base] = f2b(v);
        frow[c] = v;
    }
    __syncthreads();
    if (t < 64) {
        int lane = t;
        float fv[8];
#pragma unroll
        for (int j = 0; j < 8; j++) fv[j] = frow[lane + 64 * j];
        float lg[6];
#pragma unroll
        for (int e = 0; e < 6; e++) {
            float a = 0.f;
#pragma unroll
            for (int j = 0; j < 8; j++) a += fv[j] * gw[(lane + 64 * j) * 6 + e];
#pragma unroll
            for (int off = 32; off > 0; off >>= 1) a += __shfl_xor(a, off, 64);
            lg[e] = a + gb[e];
        }
        if (lane == 0) {
            int i1 = 0;
            float v1 = lg[0];
#pragma unroll
            for (int e = 1; e < 6; e++)
                if (lg[e] > v1) { v1 = lg[e]; i1 = e; }
            int i2 = (i1 == 0) ? 1 : 0;
            float v2 = lg[i2];
#pragma unroll
            for (int e = 0; e < 6; e++)
                if (e != i1 && lg[e] > v2) { v2 = lg[e]; i2 = e; }
            float pa = 1.f / (1.f + expf(v2 - v1));
            topi[row * 2] = i1;
            topi[row * 2 + 1] = i2;
            topp[row * 2] = pa;
            topp[row * 2 + 1] = 1.f - pa;
            int s1 = atomicAdd(cnt + i1, 1);
            int s2 = atomicAdd(cnt + i2, 1);
            rowlist[i1 * 2048 + s1] = row;
            rowlist[i2 * 2048 + s2] = row;
            slotp[row * 2] = s1;
            slotp[row * 2 + 1] = s2;
        }
    }
}

// ============ expert GEMM: compacted rows + pinned ping-pong prefetch ============
__global__ __launch_bounds__(64, 3) void moe_gemm(
    const unsigned short* __restrict__ A, long aStride,
    const unsigned short* __restrict__ Bt, const float* __restrict__ bias,
    unsigned short* __restrict__ C,
    const int* __restrict__ cnt, const int* __restrict__ rowlist) {
    int e = blockIdx.z;
    int ne = cnt[e];
    int m0 = blockIdx.x * 64;
    if (m0 >= ne) return;
    const unsigned short* Ae = A + (long)e * aStride;
    const unsigned short* Be = Bt + (long)e * 262144;
    const float* be = bias + e * 512;
    unsigned short* Ce = C + (long)e * 2048 * 512;
    int lane = threadIdx.x, l16 = lane & 15, quad = lane >> 4;
    int n0 = blockIdx.y * 64;
    long aoff[4], boff[4];
#pragma unroll
    for (int i = 0; i < 4; i++) {
        int slot = m0 + i * 16 + l16;
        int ar = rowlist ? ((slot < ne) ? rowlist[e * 2048 + slot] : 0) : slot;
        aoff[i] = (long)ar * 512 + quad * 8;
    }
#pragma unroll
    for (int j = 0; j < 4; j++) boff[j] = (long)(n0 + j * 16 + l16) * 512 + quad * 8;
    f32x4 acc[4][4];
#pragma unroll
    for (int i = 0; i < 4; i++)
#pragma unroll
        for (int j = 0; j < 4; j++)
#pragma unroll
            for (int r = 0; r < 4; r++) acc[i][j][r] = 0.f;
    bf16x8 As[2][4], Bs[2][4];
    __builtin_amdgcn_sched_barrier(0);
#pragma unroll
    for (int i = 0; i < 4; i++) As[0][i] = *(const bf16x8*)(Ae + aoff[i]);
#pragma unroll
    for (int j = 0; j < 4; j++) Bs[0][j] = *(const bf16x8*)(Be + boff[j]);
    __builtin_amdgcn_sched_barrier(0);
#pragma unroll
    for (int s = 0; s < 16; s++) {
        const int cur = s & 1;
        if (s + 1 < 16) {
            const int k1 = (s + 1) * 32;
            __builtin_amdgcn_sched_barrier(0);
#pragma unroll
            for (int i = 0; i < 4; i++) As[cur ^ 1][i] = *(const bf16x8*)(Ae + aoff[i] + k1);
#pragma unroll
            for (int j = 0; j < 4; j++) Bs[cur ^ 1][j] = *(const bf16x8*)(Be + boff[j] + k1);
            __builtin_amdgcn_sched_barrier(0);
        }
#pragma unroll
        for (int i = 0; i < 4; i++)
#pragma unroll
            for (int j = 0; j < 4; j++)
                acc[i][j] = __builtin_amdgcn_mfma_f32_16x16x32_bf16(As[cur][i], Bs[cur][j], acc[i][j], 0, 0, 0);
    }
#pragma unroll
    for (int i = 0; i < 4; i++)
#pragma unroll
        for (int j = 0; j < 4; j++) {
            int col = n0 + j * 16 + l16;
            float bcol = be[col];
#pragma unroll
            for (int r = 0; r < 4; r++) {
                int row = m0 + i * 16 + quad * 4 + r;
                float v = fmaxf(acc[i][j][r] + bcol, 0.f);
                Ce[(long)row * 512 + col] = f2b(v);
            }
        }
}

// ============ combine: unchanged ============
__global__ __launch_bounds__(256) void combine_k(
    const unsigned short* __restrict__ h2, const float* __restrict__ w3t,
    const float* __restrict__ b3, const int* __restrict__ topi,
    const float* __restrict__ topp, const int* __restrict__ slotp,
    float* __restrict__ out) {
    int b = blockIdx.x * 4 + (threadIdx.x >> 6);
    int lane = threadIdx.x & 63;
    int e0 = topi[b * 2], e1 = topi[b * 2 + 1];
    float p0 = topp[b * 2], p1 = topp[b * 2 + 1];
    int s0 = slotp[b * 2], s1 = slotp[b * 2 + 1];
    float r[12];
#pragma unroll
    for (int a = 0; a < 12; a++) r[a] = 0.f;
#pragma unroll
    for (int j = 0; j < 2; j++) {
        int e = j ? e1 : e0;
        int s = j ? s1 : s0;
        float p = j ? p1 : p0;
        const unsigned short* hp = h2 + ((long)e * 2048 + s) * 512 + lane * 8;
        bf16x8 hv = *(const bf16x8*)hp;
        float hf[8];
#pragma unroll
        for (int q = 0; q < 8; q++) hf[q] = b2f((unsigned short)hv[q]);
        const float* wb = w3t + e * 6144 + lane * 8;
#pragma unroll
        for (int a = 0; a < 12; a++) {
            float4 w0 = *(const float4*)(wb + a * 512);
            float4 w1 = *(const float4*)(wb + a * 512 + 4);
            float acc = hf[0] * w0.x + hf[1] * w0.y + hf[2] * w0.z + hf[3] * w0.w +
                        hf[4] * w1.x + hf[5] * w1.y + hf[6] * w1.z + hf[7] * w1.w;
            r[a] += p * acc;
        }
    }
#pragma unroll
    for (int a = 0; a < 12; a++)
#pragma unroll
        for (int off = 32; off > 0; off >>= 1) r[a] += __shfl_xor(r[a], off, 64);
    float v = 0.f;
#pragma unroll
    for (int a = 0; a < 12; a++)
        if (lane == a) v = r[a];
    if (lane < 12)
        out[b * 12 + lane] = v + p0 * b3[e0 * 12 + lane] + p1 * b3[e1 * 12 + lane];
}

extern "C" void kernel_launch(void* const* d_in, const int* in_sizes, int n_in,
                              void* d_out, int out_size, void* d_ws, size_t ws_size,
                              hipStream_t stream) {
    const float* x   = (const float*)d_in[0];
    const float* c1w = (const float*)d_in[1];
    const float* c1b = (const float*)d_in[2];
    const float* c2w = (const float*)d_in[3];
    const float* c2b = (const float*)d_in[4];
    const float* c3w = (const float*)d_in[5];
    const float* c3b = (const float*)d_in[6];
    const float* fcw = (const float*)d_in[7];
    const float* fcb = (const float*)d_in[8];
    const float* gw  = (const float*)d_in[9];
    const float* gb  = (const float*)d_in[10];
    const float* ew1 = (const float*)d_in[11];
    const float* eb1 = (const float*)d_in[12];
    const float* ew2 = (const float*)d_in[13];
    const float* eb2 = (const float*)d_in[14];
    const float* ew3 = (const float*)d_in[15];
    const float* eb3 = (const float*)d_in[16];

    char* ws = (char*)d_ws;
    unsigned short* y1hi = (unsigned short*)(ws + 0L);          // 52428800 B
    unsigned short* y1lo = (unsigned short*)(ws + 52428800L);   // 52428800 B
    unsigned short* f3hi = (unsigned short*)(ws + 0L);          // alias (y1 dead after conv2)
    unsigned short* f3lo = (unsigned short*)(ws + 12845056L);   // alias
    int*   cnt           = (int*)(ws + 26214400L);              // 32 B
    int*   rowlist       = (int*)(ws + 26214464L);              // 49152 B
    int*   slotp         = (int*)(ws + 26263616L);              // 16384 B
    unsigned short* y2hi = (unsigned short*)(ws + 104857600L);  // 21233664 B
    unsigned short* y2lo = (unsigned short*)(ws + 126091264L);  // 21233664 B
    unsigned short* h1   = (unsigned short*)(ws + 104857600L);  // alias (y2 dead after conv3)
    unsigned short* h2   = (unsigned short*)(ws + 117440512L);  // alias
    unsigned short* fb   = (unsigned short*)(ws + 151519232L);  // 2097152 B
    int*   topi          = (int*)(ws + 153616384L);             // 16384 B
    float* topp          = (float*)(ws + 153632768L);           // 16384 B
    unsigned short* w2h  = (unsigned short*)(ws + 153681920L);  // 65536 B
    unsigned short* w2l  = (unsigned short*)(ws + 153747456L);  // 65536 B
    unsigned short* w3h  = (unsigned short*)(ws + 153812992L);  // 73728 B
    unsigned short* w3l  = (unsigned short*)(ws + 153886720L);  // 73728 B
    unsigned short* fcwh = (unsigned short*)(ws + 153960448L);  // 3211264 B
    unsigned short* fcwl = (unsigned short*)(ws + 157171712L);  // 3211264 B
    unsigned short* ew1t = (unsigned short*)(ws + 160382976L);  // 3145728 B
    unsigned short* ew2t = (unsigned short*)(ws + 163528704L);  // 3145728 B
    float* w3t           = (float*)(ws + 166674432L);           // 147456 B
    float* Cp            = (float*)(ws + 166821888L);           // 7*4194304 = 29360128 B
    unsigned short* wb1h = (unsigned short*)(ws + 196182016L);  // 16384 B
    unsigned short* wb1l = (unsigned short*)(ws + 196198400L);  // 16384 B (end 196214784)
    float* out = (float*)d_out;

    hipLaunchKernelGGL(prep_all, dim3(3912), dim3(256), 0, stream,
                       c1w, c2w, c3w, ew3, fcw, ew1, ew2,
                       wb1h, wb1l, w2h, w2l, w3h, w3l, w3t, fcwh, fcwl, ew1t, ew2t);
    hipLaunchKernelGGL(conv1_k, dim3(6400), dim3(256), 0, stream, x, wb1h, wb1l, c1b, y1hi, y1lo);
    hipLaunchKernelGGL((convm_k<32, 20, 20, 9, 9, 2, 4, 4>), dim3(5184), dim3(64), 0, stream,
                       y1hi, y1lo, w2h, w2l, c2b, y2hi, y2lo);
    hipLaunchKernelGGL((convm_k<64, 9, 9, 7, 7, 1, 3, 3>), dim3(3136), dim3(64), 0, stream,
                       y2hi, y2lo, w3h, w3l, c3b, f3hi, f3lo);
    hipLaunchKernelGGL(fc_k, dim3(64, 8, 7), dim3(64), 0, stream, f3hi, f3lo, fcwh, fcwl, Cp, cnt);
    hipLaunchKernelGGL(fin_gate, dim3(2048), dim3(256), 0, stream, Cp, fcb, gw, gb,
                       fb, topi, topp, cnt, rowlist, slotp);
    hipLaunchKernelGGL(moe_gemm, dim3(32, 8, 6), dim3(64), 0, stream, fb, 0L, ew1t, eb1, h1,
                       cnt, rowlist);
    hipLaunchKernelGGL(moe_gemm, dim3(32, 8, 6), dim3(64), 0, stream, h1, 1048576L, ew2t, eb2, h2,
                       cnt, (const int*)nullptr);
    hipLaunchKernelGGL(combine_k, dim3(512), dim3(256), 0, stream, h2, w3t, eb3, topi, topp,
                       slotp, out);
}